// Round 6
// baseline (184.911 us; speedup 1.0000x reference)
//
#include <hip/hip_runtime.h>

// PointPillarScatter3d: scatter-mean of pillar features into BEV grid.
// R6: big-tile gather (256 cells x all 128 channels per block) with
// channel-major LDS so the output is written in 1024-B contiguous
// nontemporal wave-stores (4x larger HBM write granule than R5).
// inputs: d_in[0]=pillar_features [N,C] fp32, d_in[1]=voxel_coords [N,4] int32 (b,z,y,x)
// output: bev [B, C, NY, NX] fp32.

typedef float nfloat4 __attribute__((ext_vector_type(4)));

constexpr int NXc = 360;
constexpr int NYc = 360;
constexpr int NZc = 1;
constexpr int Cc  = 128;
constexpr int Bc  = 4;
constexpr int Sc  = NZc * NYc * NXc;   // 129600
constexpr int BSc = Bc * Sc;           // 518400

// R6 tiling
constexpr int TS   = 256;              // cells per tile
constexpr int NT2  = BSc / TS;         // 2025 tiles
constexpr int CAP2 = 192;              // max pts/tile (mean 79, +12.7 sigma)
constexpr int LROW = TS + 1;           // 257: load-phase stride -> 2-way banks (free)

// fallback (R5) tiling
constexpr int TILE  = 64;
constexpr int NTILE = BSc / TILE;      // 8100
constexpr int TCAP  = 96;
constexpr int LPAD  = Cc + 1;

// ---- R6 fill: bin points into 256-cell tiles --------------------------------
__global__ void pps_fill2(const int* __restrict__ coords,
                          int* __restrict__ cnt, int* __restrict__ list, int N) {
    int i = blockIdx.x * blockDim.x + threadIdx.x;
    if (i >= N) return;
    int4 c = reinterpret_cast<const int4*>(coords)[i];          // (b,z,y,x)
    int g = c.x * Sc + c.y * (NYc * NXc) + c.z * NXc + c.w;
    int t = g >> 8;                                             // TS=256
    int cell = g & 255;
    int slot = atomicAdd(&cnt[t], 1);
    if (slot < CAP2) list[t * CAP2 + slot] = (i << 8) | cell;   // i<2^18, fits
}

// ---- R6 gather: 1024 threads, 131.6 KB dynamic LDS --------------------------
__global__ __launch_bounds__(1024)
void pps_gather4(const float* __restrict__ feat,
                 const int* __restrict__ cnt,
                 const int* __restrict__ list,
                 float* __restrict__ out) {
    extern __shared__ float lsum[];        // [Cc][LROW] channel-major
    __shared__ int   lcnt[TS];
    __shared__ float linv[TS];
    __shared__ int   slist[CAP2];
    __shared__ int   sm;

    const int tile = blockIdx.x;
    const int t    = threadIdx.x;

    for (int k = t; k < Cc * LROW; k += 1024) lsum[k] = 0.0f;
    if (t < TS)   lcnt[t] = 0;
    if (t == 0)   sm = min(cnt[tile], CAP2);
    if (t < CAP2) slist[t] = list[tile * CAP2 + t];
    __syncthreads();

    // load phase: wave per point (lanes span channels, 256-B coalesced loads),
    // 2-deep pipelined. LDS bank: (l*257+cell)%32 = (l+cell)%32 -> 2-way, free.
    const int w = t >> 6;                  // 0..15
    const int l = t & 63;
    const int m = sm;
    for (int j = w; j < m; j += 32) {
        int e0 = slist[j];
        int j1 = j + 16;
        bool h1 = j1 < m;
        int e1 = h1 ? slist[j1] : e0;
        int p0 = e0 >> 8, c0 = e0 & 255;
        int p1 = e1 >> 8, c1 = e1 & 255;
        const float* f0 = feat + (size_t)p0 * Cc;
        const float* f1 = feat + (size_t)p1 * Cc;
        float a0 = f0[l];
        float a1 = f0[l + 64];
        float b0 = f1[l];
        float b1 = f1[l + 64];
        atomicAdd(&lsum[l * LROW + c0],        a0);
        atomicAdd(&lsum[(l + 64) * LROW + c0], a1);
        if (l == 0) atomicAdd(&lcnt[c0], 1);
        if (h1) {
            atomicAdd(&lsum[l * LROW + c1],        b0);
            atomicAdd(&lsum[(l + 64) * LROW + c1], b1);
            if (l == 0) atomicAdd(&lcnt[c1], 1);
        }
    }
    __syncthreads();

    if (t < TS) {
        int n = lcnt[t];
        linv[t] = n > 0 ? 1.0f / (float)n : 0.0f;
    }
    __syncthreads();

    // write phase: wave = one channel per iteration; 64 lanes x float4 =
    // 1024 B fully contiguous nontemporal store per instruction.
    const int g0 = tile * TS;
    const int b0 = g0 / Sc;
    const int s0 = g0 - b0 * Sc;
    const bool straddle = (s0 + TS > Sc);   // 3 tiles cross batch boundary

    if (!straddle) {
        float* ob = out + (size_t)b0 * Cc * Sc + s0;
        #pragma unroll
        for (int k = 0; k < 8; ++k) {
            int c = w * 8 + k;
            nfloat4 v  = *reinterpret_cast<const nfloat4*>(&lsum[c * LROW + 4 * l]);
            nfloat4 iv = *reinterpret_cast<const nfloat4*>(&linv[4 * l]);
            nfloat4 o  = v * iv;
            __builtin_nontemporal_store(o, reinterpret_cast<nfloat4*>(ob + (size_t)c * Sc + 4 * l));
        }
    } else {
        for (int k = 0; k < 8; ++k) {
            int c = w * 8 + k;
            for (int k2 = 0; k2 < 4; ++k2) {
                int cell = 4 * l + k2;
                int gg = g0 + cell;
                int bb = gg / Sc;
                int ss = gg - bb * Sc;
                out[((size_t)bb * Cc + c) * Sc + ss] = lsum[c * LROW + cell] * linv[cell];
            }
        }
    }
}

// ---- fallback path (R5: 64-cell tiles, 34 KB static LDS) --------------------
__global__ void pps_fill_tiles(const int* __restrict__ coords,
                               int* __restrict__ tile_cnt,
                               int* __restrict__ tile_list, int N) {
    int i = blockIdx.x * blockDim.x + threadIdx.x;
    if (i >= N) return;
    int4 c = reinterpret_cast<const int4*>(coords)[i];
    int gidx = c.x * Sc + c.y * (NYc * NXc) + c.z * NXc + c.w;
    int tile = gidx >> 6;
    int cell = gidx & 63;
    int slot = atomicAdd(&tile_cnt[tile], 1);
    if (slot < TCAP) tile_list[tile * TCAP + slot] = (i << 6) | cell;
}

__global__ __launch_bounds__(512)
void pps_gather3(const float* __restrict__ feat,
                 const int* __restrict__ tile_cnt,
                 const int* __restrict__ tile_list,
                 float* __restrict__ out) {
    __shared__ float lsum[TILE * LPAD];
    __shared__ float linv[TILE];
    __shared__ int   lcnt[TILE];
    __shared__ int   slist[TCAP];
    __shared__ int   sm;

    const int tile = blockIdx.x;
    const int t    = threadIdx.x;

    for (int k = t; k < TILE * LPAD; k += 512) lsum[k] = 0.0f;
    if (t < TILE) lcnt[t] = 0;
    if (t == 0)   sm = min(tile_cnt[tile], TCAP);
    if (t < TCAP) slist[t] = tile_list[tile * TCAP + t];
    __syncthreads();

    const int wave = t >> 6;
    const int lane = t & 63;
    const int m = sm;
    for (int j = wave; j < m; j += 16) {
        int e0 = slist[j];
        int j1 = j + 8;
        bool h1 = j1 < m;
        int e1 = h1 ? slist[j1] : e0;
        int p0 = e0 >> 6, cell0 = e0 & 63;
        int p1 = e1 >> 6, cell1 = e1 & 63;
        const float* f0 = feat + (size_t)p0 * Cc;
        const float* f1 = feat + (size_t)p1 * Cc;
        float a0 = f0[lane];
        float a1 = f0[lane + 64];
        float b0 = f1[lane];
        float b1 = f1[lane + 64];
        atomicAdd(&lsum[cell0 * LPAD + lane],      a0);
        atomicAdd(&lsum[cell0 * LPAD + lane + 64], a1);
        if (lane == 0) atomicAdd(&lcnt[cell0], 1);
        if (h1) {
            atomicAdd(&lsum[cell1 * LPAD + lane],      b0);
            atomicAdd(&lsum[cell1 * LPAD + lane + 64], b1);
            if (lane == 0) atomicAdd(&lcnt[cell1], 1);
        }
    }
    __syncthreads();

    if (t < TILE) {
        int n = lcnt[t];
        linv[t] = n > 0 ? 1.0f / (float)n : 0.0f;
    }
    __syncthreads();

    const int b  = tile / (Sc / TILE);
    const int s0 = (tile % (Sc / TILE)) * TILE;
    float* ob = out + (size_t)b * Cc * Sc + s0;
    #pragma unroll
    for (int iter = 0; iter < 4; ++iter) {
        int idx = iter * 512 + t;
        int c   = idx >> 4;
        int sg  = (idx & 15) * 4;
        nfloat4 o;
        o.x = lsum[(sg + 0) * LPAD + c] * linv[sg + 0];
        o.y = lsum[(sg + 1) * LPAD + c] * linv[sg + 1];
        o.z = lsum[(sg + 2) * LPAD + c] * linv[sg + 2];
        o.w = lsum[(sg + 3) * LPAD + c] * linv[sg + 3];
        __builtin_nontemporal_store(o, reinterpret_cast<nfloat4*>(ob + (size_t)c * Sc + sg));
    }
}

// ---- launch -----------------------------------------------------------------
extern "C" void kernel_launch(void* const* d_in, const int* in_sizes, int n_in,
                              void* d_out, int out_size, void* d_ws, size_t ws_size,
                              hipStream_t stream) {
    const float* feat   = reinterpret_cast<const float*>(d_in[0]);
    const int*   coords = reinterpret_cast<const int*>(d_in[1]);
    float*       out    = reinterpret_cast<float*>(d_out);

    const int N = in_sizes[0] / Cc;  // 160000

    const size_t lds_bytes = (size_t)Cc * LROW * sizeof(float);   // 131584 B
    // hipFuncSetAttribute is a host-side (non-stream) call: graph-capture-safe,
    // idempotent, deterministic.
    hipError_t ae = hipFuncSetAttribute(
        reinterpret_cast<const void*>(pps_gather4),
        hipFuncAttributeMaxDynamicSharedMemorySize, (int)lds_bytes);

    const size_t cnt2_bytes  = (size_t)NT2 * sizeof(int);         // 8.1 KB
    const size_t list2_bytes = (size_t)NT2 * CAP2 * sizeof(int);  // 1.56 MB

    if (ae == hipSuccess && ws_size >= cnt2_bytes + list2_bytes) {
        // R6 path
        int* cnt2  = reinterpret_cast<int*>(d_ws);
        int* list2 = reinterpret_cast<int*>((char*)d_ws + cnt2_bytes);
        (void)hipMemsetAsync(d_ws, 0, cnt2_bytes, stream);
        {
            int threads = 256;
            int blocks = (N + threads - 1) / threads;
            pps_fill2<<<blocks, threads, 0, stream>>>(coords, cnt2, list2, N);
        }
        pps_gather4<<<NT2, 1024, lds_bytes, stream>>>(feat, cnt2, list2, out);
    } else {
        // fallback: R5 path (34 KB static LDS)
        const size_t tcnt_bytes = (size_t)NTILE * sizeof(int);
        int* tile_cnt  = reinterpret_cast<int*>(d_ws);
        int* tile_list = reinterpret_cast<int*>((char*)d_ws + tcnt_bytes);
        (void)hipMemsetAsync(d_ws, 0, tcnt_bytes, stream);
        {
            int threads = 256;
            int blocks = (N + threads - 1) / threads;
            pps_fill_tiles<<<blocks, threads, 0, stream>>>(coords, tile_cnt, tile_list, N);
        }
        pps_gather3<<<NTILE, 512, 0, stream>>>(feat, tile_cnt, tile_list, out);
    }
}

// Round 7
// 147.943 us; speedup vs baseline: 1.2499x; 1.2499x over previous
//
#include <hip/hip_runtime.h>

// PointPillarScatter3d: scatter-mean of pillar features into BEV grid.
// R7: channel-split tiles for near-sequential HBM writes.
//   block = (s_tile of 540 cells) x (16 channels); grid = st*8+cg so resident
//   blocks cover adjacent s_tiles -> each (b,c) output plane is written in
//   near-address-order 2.16KB segments (sequential DRAM streams).
//   All LDS access conflict-free; 4 blocks/CU x 8 waves = 32 waves/CU.
// inputs: d_in[0]=pillar_features [N,128] fp32, d_in[1]=voxel_coords [N,4] int32 (b,z,y,x)
// output: bev [4, 128, 360, 360] fp32.

typedef float nfloat4 __attribute__((ext_vector_type(4)));

constexpr int NXc = 360;
constexpr int NYc = 360;
constexpr int NZc = 1;
constexpr int Cc  = 128;
constexpr int Bc  = 4;
constexpr int Sc  = NZc * NYc * NXc;   // 129600
constexpr int BSc = Bc * Sc;           // 518400

// R7 tiling
constexpr int TSC   = 540;             // cells per s-tile (129600/540 = 240: no batch straddle)
constexpr int NST   = BSc / TSC;       // 960 s-tiles
constexpr int CHG   = 16;              // channels per block
constexpr int NCG   = Cc / CHG;        // 8 channel groups
constexpr int CAP3  = 240;             // max pts/s-tile (mean 166.7, sd 12.9; realized max ~215)
constexpr int LSTR  = TSC + 1;         // 541: (29*ch+cell)%32 -> 16 distinct banks per point
constexpr int CSTRIDE = 16;            // pad tile counters to one per 64B line (atomic contention)

// ---- fill: bin points into 540-cell s-tiles ---------------------------------
__global__ void pps_fill3(const int* __restrict__ coords,
                          int* __restrict__ cnt, int* __restrict__ list, int N) {
    int i = blockIdx.x * blockDim.x + threadIdx.x;
    if (i >= N) return;
    int4 c = reinterpret_cast<const int4*>(coords)[i];          // (b,z,y,x)
    int g = c.x * Sc + c.y * (NYc * NXc) + c.z * NXc + c.w;     // 0..BSc-1
    int st = g / TSC;                                           // magic-mul div
    int cell = g - st * TSC;                                    // 0..539 (10 bits)
    int slot = atomicAdd(&cnt[st * CSTRIDE], 1);
    if (slot < CAP3) list[st * CAP3 + slot] = (i << 10) | cell; // i<2^18: fits
}

// ---- gather: block = s_tile x 16 channels -----------------------------------
__global__ __launch_bounds__(512)
void pps_gather5(const float* __restrict__ feat,
                 const int* __restrict__ cnt,
                 const int* __restrict__ list,
                 float* __restrict__ out) {
    __shared__ __align__(16) float lsum[CHG * LSTR];   // 16 x 541 = 33.8 KB
    __shared__ int   lcnt[TSC];                        // 2.16 KB
    __shared__ float linv[TSC];                        // 2.16 KB
    __shared__ int   slist[CAP3];                      // 960 B
    __shared__ int   sm;

    const int st = blockIdx.x >> 3;     // s-tile (adjacent bids -> adjacent tiles)
    const int cg = blockIdx.x & 7;      // channel group
    const int t  = threadIdx.x;

    // zero lsum (float4: 16*541 = 8656 = 4*2164), lcnt; preload list
    for (int k = t; k < (CHG * LSTR) / 4; k += 512)
        reinterpret_cast<nfloat4*>(lsum)[k] = (nfloat4)0.0f;
    for (int k = t; k < TSC; k += 512) lcnt[k] = 0;
    if (t == 0) sm = min(cnt[st * CSTRIDE], CAP3);
    if (t < CAP3) slist[t] = list[st * CAP3 + t];
    __syncthreads();

    // load phase: wave-instr = 4 points x 16 channels (64B full-line per point).
    // LDS atomics: addr = ch*541+cell -> banks (29ch+cell)%32: 16 distinct/point.
    const int w    = t >> 6;            // 0..7
    const int l    = t & 63;
    const int psub = l >> 4;            // 0..3: point within quad
    const int ch   = l & 15;            // channel within group
    const int m    = sm;
    #pragma unroll 2
    for (int sb = w * 4; sb < m; sb += 32) {
        int slot = sb + psub;
        bool ok = slot < m;
        int e    = slist[ok ? slot : 0];
        int cell = e & 1023;
        int p    = e >> 10;
        if (ok) {
            float v = feat[(size_t)p * Cc + cg * CHG + ch];
            atomicAdd(&lsum[ch * LSTR + cell], v);
            if (ch == 0) atomicAdd(&lcnt[cell], 1);
        }
    }
    __syncthreads();

    for (int k = t; k < TSC; k += 512) {
        int n = lcnt[k];
        linv[k] = n > 0 ? 1.0f / (float)n : 0.0f;
    }
    __syncthreads();

    // write phase: scalar stores, lanes span consecutive cells (conflict-free
    // LDS stride-1 reads; 256B-contiguous global stores; plane written in
    // address order across adjacent blocks).
    const int b  = st / (Sc / TSC);               // st/240
    const int s0 = (st % (Sc / TSC)) * TSC;
    float* ob = out + ((size_t)b * Cc + cg * CHG) * Sc + s0;
    #pragma unroll
    for (int i = 0; i < 17; ++i) {
        int idx = i * 512 + t;                    // 0..8639
        if (idx < CHG * TSC) {
            int cl  = idx / TSC;                  // 0..15 (magic-mul)
            int pos = idx - cl * TSC;             // 0..539
            float val = lsum[cl * LSTR + pos] * linv[pos];
            __builtin_nontemporal_store(val, ob + (size_t)cl * Sc + pos);
        }
    }
}

// ---- fallback (R1 atomic scatter; used only if ws too small) ----------------
__global__ void pps_count_kernel(const int* __restrict__ coords,
                                 int* __restrict__ cnt, int N) {
    int i = blockIdx.x * blockDim.x + threadIdx.x;
    if (i >= N) return;
    int4 c = reinterpret_cast<const int4*>(coords)[i];
    int gidx = c.x * Sc + c.y * (NYc * NXc) + c.z * NXc + c.w;
    atomicAdd(&cnt[gidx], 1);
}

__global__ void pps_scatter_kernel(const float* __restrict__ feat,
                                   const int* __restrict__ coords,
                                   const int* __restrict__ cnt,
                                   float* __restrict__ out, int N) {
    int t = blockIdx.x * blockDim.x + threadIdx.x;
    int i = t >> 5;
    int g = t & 31;
    if (i >= N) return;
    int4 c = reinterpret_cast<const int4*>(coords)[i];
    int s    = c.y * (NYc * NXc) + c.z * NXc + c.w;
    int gidx = c.x * Sc + s;
    int n = cnt[gidx];
    float4 v = reinterpret_cast<const float4*>(feat + (size_t)i * Cc)[g];
    float* base = out + ((size_t)c.x * Cc + (size_t)g * 4) * Sc + s;
    if (n == 1) {
        base[0 * (size_t)Sc] = v.x;
        base[1 * (size_t)Sc] = v.y;
        base[2 * (size_t)Sc] = v.z;
        base[3 * (size_t)Sc] = v.w;
    } else {
        float inv = 1.0f / (float)n;
        atomicAdd(&base[0 * (size_t)Sc], v.x * inv);
        atomicAdd(&base[1 * (size_t)Sc], v.y * inv);
        atomicAdd(&base[2 * (size_t)Sc], v.z * inv);
        atomicAdd(&base[3 * (size_t)Sc], v.w * inv);
    }
}

// ---- launch -----------------------------------------------------------------
extern "C" void kernel_launch(void* const* d_in, const int* in_sizes, int n_in,
                              void* d_out, int out_size, void* d_ws, size_t ws_size,
                              hipStream_t stream) {
    const float* feat   = reinterpret_cast<const float*>(d_in[0]);
    const int*   coords = reinterpret_cast<const int*>(d_in[1]);
    float*       out    = reinterpret_cast<float*>(d_out);

    const int N = in_sizes[0] / Cc;  // 160000

    const size_t cnt_bytes  = (size_t)NST * CSTRIDE * sizeof(int);   // 61.4 KB
    const size_t list_bytes = (size_t)NST * CAP3 * sizeof(int);      // 921.6 KB

    if (ws_size >= cnt_bytes + list_bytes) {
        int* cnt  = reinterpret_cast<int*>(d_ws);
        int* list = reinterpret_cast<int*>((char*)d_ws + cnt_bytes);
        (void)hipMemsetAsync(d_ws, 0, cnt_bytes, stream);
        {
            int threads = 256;
            int blocks = (N + threads - 1) / threads;
            pps_fill3<<<blocks, threads, 0, stream>>>(coords, cnt, list, N);
        }
        pps_gather5<<<NST * NCG, 512, 0, stream>>>(feat, cnt, list, out);
    } else {
        // fallback: R1 atomic scatter
        int* cnt = reinterpret_cast<int*>(d_ws);
        (void)hipMemsetAsync(d_out, 0, (size_t)out_size * sizeof(float), stream);
        (void)hipMemsetAsync(d_ws, 0, (size_t)BSc * sizeof(int), stream);
        {
            int threads = 256;
            int blocks = (N + threads - 1) / threads;
            pps_count_kernel<<<blocks, threads, 0, stream>>>(coords, cnt, N);
        }
        {
            int threads = 256;
            long long total = (long long)N * 32;
            int blocks = (int)((total + threads - 1) / threads);
            pps_scatter_kernel<<<blocks, threads, 0, stream>>>(feat, coords, cnt, out, N);
        }
    }
}